// Round 1
// baseline (825.282 us; speedup 1.0000x reference)
//
#include <hip/hip_runtime.h>

#define D        32000
#define DV       8000          // D/4 float4s per row
#define BLOCK    512
#define NWAVES   (BLOCK / 64)  // 8
#define NCHUNK   16            // ceil(8000/512)
#define FULLC    15            // chunks with no bounds check
#define TAILLIM  320           // 8000 - 15*512

__device__ __forceinline__ float wave_reduce_sum(float v) {
    v += __shfl_xor(v, 32, 64);
    v += __shfl_xor(v, 16, 64);
    v += __shfl_xor(v,  8, 64);
    v += __shfl_xor(v,  4, 64);
    v += __shfl_xor(v,  2, 64);
    v += __shfl_xor(v,  1, 64);
    return v;
}

__device__ __forceinline__ float wave_reduce_max(float v) {
    v = fmaxf(v, __shfl_xor(v, 32, 64));
    v = fmaxf(v, __shfl_xor(v, 16, 64));
    v = fmaxf(v, __shfl_xor(v,  8, 64));
    v = fmaxf(v, __shfl_xor(v,  4, 64));
    v = fmaxf(v, __shfl_xor(v,  2, 64));
    v = fmaxf(v, __shfl_xor(v,  1, 64));
    return v;
}

// One block per row. Row data (u = 1 + 0.5*X) lives in registers:
// 512 threads x 16 float4 = 64 data VGPRs/thread.
// launch_bounds(512,4): VGPR cap 128 -> 2 blocks/CU so one block's
// load/store overlaps another block's compute phase.
__global__ __launch_bounds__(BLOCK, 4) void tsallis_secant_kernel(
        const float* __restrict__ X, float* __restrict__ out) {
    const int row  = blockIdx.x;
    const int tid  = threadIdx.x;
    const int wave = tid >> 6;
    const int lane = tid & 63;

    __shared__ float sbuf[2][NWAVES];

    const float4* __restrict__ Xv = (const float4*)(X + (size_t)row * D);
    float4* __restrict__ Ov       = (float4*)(out + (size_t)row * D);

    // ---- load + transform u = 1 + 0.5*X, track max ----
    float4 u[NCHUNK];
    float m = -1e30f;
#pragma unroll
    for (int i = 0; i < NCHUNK; ++i) {
        if (i < FULLC || tid < TAILLIM) {
            float4 x = Xv[i * BLOCK + tid];
            float4 uu;
            uu.x = fmaf(0.5f, x.x, 1.0f);
            uu.y = fmaf(0.5f, x.y, 1.0f);
            uu.z = fmaf(0.5f, x.z, 1.0f);
            uu.w = fmaf(0.5f, x.w, 1.0f);
            u[i] = uu;
            m = fmaxf(m, fmaxf(fmaxf(uu.x, uu.y), fmaxf(uu.z, uu.w)));
        } else {
            u[i] = make_float4(-1e30f, -1e30f, -1e30f, -1e30f); // relu -> 0
        }
    }

    // ---- block max of u ----
    m = wave_reduce_max(m);
    if (lane == 0) sbuf[0][wave] = m;
    __syncthreads();
    float umax = sbuf[0][0];
#pragma unroll
    for (int w = 1; w < NWAVES; ++w) umax = fmaxf(umax, sbuf[0][w]);
    __syncthreads();  // sbuf[0] reusable afterwards

    // t = 0.5*tau.  tau_lo = max_val -> t_lo = umax - 1.
    // tau_hi = max_val + 2 - 2/sqrt(d) -> t_hi = umax - 1/sqrt(d).
    float t_lo = umax - 1.0f;
    float t_hi = umax - 0.00559016994f;  // 1/sqrt(32000)

    int parity = 0;

    // f(t) = sum relu(u - t)^2 - 1, block-wide (every thread gets identical f)
    auto feval = [&](float t) -> float {
        float a0 = 0.f, a1 = 0.f, a2 = 0.f, a3 = 0.f;
#pragma unroll
        for (int i = 0; i < NCHUNK; ++i) {
            float v;
            v = fmaxf(u[i].x - t, 0.f); a0 = fmaf(v, v, a0);
            v = fmaxf(u[i].y - t, 0.f); a1 = fmaf(v, v, a1);
            v = fmaxf(u[i].z - t, 0.f); a2 = fmaf(v, v, a2);
            v = fmaxf(u[i].w - t, 0.f); a3 = fmaf(v, v, a3);
        }
        float s = wave_reduce_sum((a0 + a1) + (a2 + a3));
        if (lane == 0) sbuf[parity][wave] = s;
        __syncthreads();
        float f = sbuf[parity][0];
#pragma unroll
        for (int w = 1; w < NWAVES; ++w) f += sbuf[parity][w];
        parity ^= 1;
        return f - 1.0f;
    };

    float f_lo = feval(t_lo);
    float f_hi = feval(t_hi);

    // Secant; reference's converged state is a fixed point -> early exit
    // reproduces all 100 reference iterations exactly.
    for (int it = 0; it < 100; ++it) {
        float diff = f_lo - f_hi;
        if (diff * diff < 1e-5f) break;          // block-uniform branch
        float t_new = (t_lo * f_hi - t_hi * f_lo) / (f_hi - f_lo);
        t_lo = t_hi;
        f_lo = f_hi;
        t_hi = t_new;
        f_hi = feval(t_hi);
    }

    // ---- invariant: p_hi = relu(u - t_hi)^2 ----
    const float t = t_hi;
#pragma unroll
    for (int i = 0; i < NCHUNK; ++i) {
        if (i < FULLC || tid < TAILLIM) {
            float4 p; float v;
            v = fmaxf(u[i].x - t, 0.f); p.x = v * v;
            v = fmaxf(u[i].y - t, 0.f); p.y = v * v;
            v = fmaxf(u[i].z - t, 0.f); p.z = v * v;
            v = fmaxf(u[i].w - t, 0.f); p.w = v * v;
            Ov[i * BLOCK + tid] = p;
        }
    }
}

extern "C" void kernel_launch(void* const* d_in, const int* in_sizes, int n_in,
                              void* d_out, int out_size, void* d_ws, size_t ws_size,
                              hipStream_t stream) {
    const float* X = (const float*)d_in[0];
    float* out     = (float*)d_out;
    const int rows = in_sizes[0] / D;  // 4096
    tsallis_secant_kernel<<<rows, BLOCK, 0, stream>>>(X, out);
}

// Round 2
// 823.251 us; speedup vs baseline: 1.0025x; 1.0025x over previous
//
#include <hip/hip_runtime.h>

#define D        32000
#define BLOCK    512
#define NWAVES   (BLOCK / 64)  // 8
#define NCHUNK   16            // ceil(8000/512) float4 chunks
#define FULLC    15            // chunks with no bounds check
#define TAILLIM  320           // 8000 - 15*512
#define CAP      2048          // candidate list capacity (expect ~650)
#define CPT      (CAP / BLOCK) // 4 candidates per thread

#define NEGBIG   -1e30f

__device__ __forceinline__ float wave_reduce_sum(float v) {
    v += __shfl_xor(v, 32, 64);
    v += __shfl_xor(v, 16, 64);
    v += __shfl_xor(v,  8, 64);
    v += __shfl_xor(v,  4, 64);
    v += __shfl_xor(v,  2, 64);
    v += __shfl_xor(v,  1, 64);
    return v;
}

__device__ __forceinline__ float wave_reduce_max(float v) {
    v = fmaxf(v, __shfl_xor(v, 32, 64));
    v = fmaxf(v, __shfl_xor(v, 16, 64));
    v = fmaxf(v, __shfl_xor(v,  8, 64));
    v = fmaxf(v, __shfl_xor(v,  4, 64));
    v = fmaxf(v, __shfl_xor(v,  2, 64));
    v = fmaxf(v, __shfl_xor(v,  1, 64));
    return v;
}

// One block per row. Raw x lives in registers (64 VGPRs/thread); the secant
// loop runs on a compacted candidate list (u > umax-1, ~650 of 32000 elems,
// <=4 regs/thread) -- elements below umax-1 contribute 0 to f(t) for every
// iterate t >= umax-1. Block-uniform fallback to the full-register feval if
// an iterate dips below umax-1 or the list overflows (never for Gaussian).
__global__ __launch_bounds__(BLOCK, 4) void tsallis_secant_kernel(
        const float* __restrict__ X, float* __restrict__ out) {
    const int row  = blockIdx.x;
    const int tid  = threadIdx.x;
    const int wave = tid >> 6;
    const int lane = tid & 63;

    __shared__ float sbuf[2][NWAVES];
    __shared__ float list[CAP];
    __shared__ int   s_cnt;
    __shared__ float s_max;

    const float4* __restrict__ Xv = (const float4*)(X + (size_t)row * D);
    float4* __restrict__ Ov       = (float4*)(out + (size_t)row * D);

    if (tid == 0) s_cnt = 0;

    // ---- load raw x, track max (u = 1 + 0.5x is order-preserving) ----
    float4 x[NCHUNK];
    float mx = NEGBIG;
#pragma unroll
    for (int i = 0; i < NCHUNK; ++i) {
        if (i < FULLC || tid < TAILLIM) {
            float4 xv = Xv[i * BLOCK + tid];
            x[i] = xv;
            mx = fmaxf(mx, fmaxf(fmaxf(xv.x, xv.y), fmaxf(xv.z, xv.w)));
        } else {
            x[i] = make_float4(NEGBIG, NEGBIG, NEGBIG, NEGBIG);
        }
    }

    // ---- block max of x ----
    mx = wave_reduce_max(mx);
    if (lane == 0) sbuf[0][wave] = mx;
    __syncthreads();
    float xmax = sbuf[0][0];
#pragma unroll
    for (int w = 1; w < NWAVES; ++w) xmax = fmaxf(xmax, sbuf[0][w]);

    const float umax    = fmaf(0.5f, xmax, 1.0f);
    const float t_floor = umax - 1.0f;           // = t_lo
    const float xcut    = xmax - 2.0f;           // x > xcut  <=>  u > t_floor

    // ---- compact candidates (u-values) into LDS ----
    int nloc = 0;
#pragma unroll
    for (int i = 0; i < NCHUNK; ++i) {
        nloc += (x[i].x > xcut) + (x[i].y > xcut) +
                (x[i].z > xcut) + (x[i].w > xcut);
    }
    __syncthreads();  // sbuf[0] reads done before reuse; s_cnt=0 visible
    int base = (nloc > 0) ? atomicAdd(&s_cnt, nloc) : 0;
#pragma unroll
    for (int i = 0; i < NCHUNK; ++i) {
        float xs[4] = {x[i].x, x[i].y, x[i].z, x[i].w};
#pragma unroll
        for (int k = 0; k < 4; ++k) {
            if (xs[k] > xcut) {
                if (base < CAP) list[base] = fmaf(0.5f, xs[k], 1.0f);
                ++base;
            }
        }
    }
    __syncthreads();
    const int  cnt = s_cnt;
    const bool ok  = (cnt <= CAP);

    // ---- park candidates in registers ----
    float c[CPT];
#pragma unroll
    for (int k = 0; k < CPT; ++k) {
        int idx = tid + k * BLOCK;
        c[k] = (idx < cnt) ? list[idx] : NEGBIG;
    }

    int parity = 0;
    auto block_sum = [&](float partial) -> float {
        float s = wave_reduce_sum(partial);
        if (lane == 0) sbuf[parity][wave] = s;
        __syncthreads();
        float f = sbuf[parity][0];
#pragma unroll
        for (int w = 1; w < NWAVES; ++w) f += sbuf[parity][w];
        parity ^= 1;
        return f;
    };

    // f(t) = sum relu(u - t)^2 - 1
    auto feval_fast = [&](float t) -> float {
        float a = 0.f;
#pragma unroll
        for (int k = 0; k < CPT; ++k) {
            float v = fmaxf(c[k] - t, 0.f);
            a = fmaf(v, v, a);
        }
        return block_sum(a) - 1.0f;
    };
    auto feval_full = [&](float t) -> float {
        const float omt = 1.0f - t;  // u - t = fma(0.5, x, 1-t)
        float a0 = 0.f, a1 = 0.f, a2 = 0.f, a3 = 0.f;
#pragma unroll
        for (int i = 0; i < NCHUNK; ++i) {
            float v;
            v = fmaxf(fmaf(0.5f, x[i].x, omt), 0.f); a0 = fmaf(v, v, a0);
            v = fmaxf(fmaf(0.5f, x[i].y, omt), 0.f); a1 = fmaf(v, v, a1);
            v = fmaxf(fmaf(0.5f, x[i].z, omt), 0.f); a2 = fmaf(v, v, a2);
            v = fmaxf(fmaf(0.5f, x[i].w, omt), 0.f); a3 = fmaf(v, v, a3);
        }
        return block_sum((a0 + a1) + (a2 + a3)) - 1.0f;
    };
    auto feval = [&](float t) -> float {
        // block-uniform selector (t, t_floor, ok identical across threads)
        return (ok && t >= t_floor) ? feval_fast(t) : feval_full(t);
    };

    // t = 0.5*tau.  tau_lo = max_val -> t_lo = umax - 1.
    // tau_hi = max_val + 2 - 2/sqrt(d) -> t_hi = umax - 1/sqrt(d).
    float t_lo = t_floor;
    float t_hi = umax - 0.00559016994f;  // 1/sqrt(32000)

    float f_lo = feval(t_lo);
    float f_hi = feval(t_hi);

    // Secant; reference's converged state is a fixed point -> early exit
    // reproduces all 100 reference iterations exactly.
    for (int it = 0; it < 100; ++it) {
        float diff = f_lo - f_hi;
        if (diff * diff < 1e-5f) break;          // block-uniform branch
        float t_new = (t_lo * f_hi - t_hi * f_lo) / (f_hi - f_lo);
        t_lo = t_hi;
        f_lo = f_hi;
        t_hi = t_new;
        f_hi = feval(t_hi);
    }

    // ---- p = relu(u - t)^2, u - t = fma(0.5, x, 1-t) ----
    const float omt = 1.0f - t_hi;
#pragma unroll
    for (int i = 0; i < NCHUNK; ++i) {
        if (i < FULLC || tid < TAILLIM) {
            float4 p; float v;
            v = fmaxf(fmaf(0.5f, x[i].x, omt), 0.f); p.x = v * v;
            v = fmaxf(fmaf(0.5f, x[i].y, omt), 0.f); p.y = v * v;
            v = fmaxf(fmaf(0.5f, x[i].z, omt), 0.f); p.z = v * v;
            v = fmaxf(fmaf(0.5f, x[i].w, omt), 0.f); p.w = v * v;
            Ov[i * BLOCK + tid] = p;
        }
    }
}

extern "C" void kernel_launch(void* const* d_in, const int* in_sizes, int n_in,
                              void* d_out, int out_size, void* d_ws, size_t ws_size,
                              hipStream_t stream) {
    const float* X = (const float*)d_in[0];
    float* out     = (float*)d_out;
    const int rows = in_sizes[0] / D;  // 4096
    tsallis_secant_kernel<<<rows, BLOCK, 0, stream>>>(X, out);
}